// Round 8
// baseline (388.283 us; speedup 1.0000x reference)
//
#include <hip/hip_runtime.h>
#include <math.h>

#define BB 32
#define LL 1024
#define CC 1024
#define EE 64
#define TASKS 8
#define CHUNKS 256               // chunks per batch row
#define NBLK (BB * CHUNKS)       // 8192 blocks
#define SPIN_LIMIT 50000         // ~10ms patience, then self-compute fallback

typedef float f32x4 __attribute__((ext_vector_type(4)));

struct GateLDS {
    float hg[CC];        // 4 KB
    float part[4][EE];   // 1 KB
    float res[4];        // g1, g2, bits(i1), bits(i2)
    float pt[EE];        // 256 B
};

__device__ __forceinline__ float gelu_exact(float x) {
    // gelu(x) = 0.5*x*(1+erf(x/sqrt(2))), approximate=False
    return 0.5f * x * (1.0f + erff(x * 0.7071067811865476f));
}

// Streaming store: sc0 sc1 nt (measured best in R6/R7)
__device__ __forceinline__ void store_stream(f32x4 v, f32x4* p) {
    asm volatile("global_store_dwordx4 %0, %1, off sc0 sc1 nt"
                 :: "v"(p), "v"(v) : "memory");
}

// Full gate for batch row b with 256 threads. Fills gl.res (g1,g2,i1,i2 bits)
// and gl.pt (thresholded probs). Deterministic: identical bits whoever runs it.
__device__ void gate_compute(int b,
                             const float* __restrict__ x2,
                             const float* __restrict__ W1,
                             const float* __restrict__ b1,
                             const float* __restrict__ W2,
                             GateLDS& gl)
{
    const int tid = threadIdx.x;   // 256
    float xv[TASKS];
#pragma unroll
    for (int t = 0; t < TASKS; ++t) xv[t] = x2[b * TASKS + t];

    // hgate = gelu(x2 @ W1 + b1)
#pragma unroll
    for (int r = 0; r < 4; ++r) {
        const int c = tid + (r << 8);
        float acc = b1[c];
#pragma unroll
        for (int t = 0; t < TASKS; ++t) acc += xv[t] * W1[t * CC + c];
        gl.hg[c] = gelu_exact(acc);
    }
    __syncthreads();

    // logits[e] = sum_c hg[c]*W2[c,e]; wave w owns c = w, w+4, ... (coalesced)
    const int wave = tid >> 6;
    const int lane = tid & 63;
    {
        float acc = 0.f;
#pragma unroll 8
        for (int j = 0; j < 256; ++j) {
            const int c = wave + (j << 2);
            acc += gl.hg[c] * W2[c * 128 + lane];
        }
        gl.part[wave][lane] = acc;
    }
    __syncthreads();

    // wave 0: cross-wave reduce, softmax, top-2 (lowest-index ties)
    if (tid < EE) {
        float v = gl.part[0][tid] + gl.part[1][tid] + gl.part[2][tid] + gl.part[3][tid];
        float m = v;
#pragma unroll
        for (int off = 32; off; off >>= 1) m = fmaxf(m, __shfl_xor(m, off));
        float ex = expf(v - m);
        float sum = ex;
#pragma unroll
        for (int off = 32; off; off >>= 1) sum += __shfl_xor(sum, off);
        float p = ex / sum + 1e-4f;

        float bv = p; int bi = tid;
#pragma unroll
        for (int off = 32; off; off >>= 1) {
            float ov = __shfl_xor(bv, off);
            int   oi = __shfl_xor(bi, off);
            if (ov > bv || (ov == bv && oi < bi)) { bv = ov; bi = oi; }
        }
        float p2 = (tid == bi) ? -1.f : p;
        float bv2 = p2; int bi2 = tid;
#pragma unroll
        for (int off = 32; off; off >>= 1) {
            float ov = __shfl_xor(bv2, off);
            int   oi = __shfl_xor(bi2, off);
            if (ov > bv2 || (ov == bv2 && oi < bi2)) { bv2 = ov; bi2 = oi; }
        }
        gl.pt[tid] = (p >= bv2) ? p : 0.f;
        if (tid == 0) {
            gl.res[0] = bv;
            gl.res[1] = bv2;
            gl.res[2] = __int_as_float(bi);
            gl.res[3] = __int_as_float(bi2);
        }
    }
    __syncthreads();
}

// Single fused kernel. Block blk: b = blk&31, chunk = blk>>5.
// chunk==0 blocks (first dispatched) produce the gate scalars + Pt, then
// release `flag`. All blocks pre-issue their x loads, wait (bounded spin +
// self-compute fallback => dispatch-order independent), scale, stream-store.
// Early consumer blocks (chunks 1..3) also do the tiny mask reductions.
__global__ void __launch_bounds__(256)
fused_kernel(const f32x4* __restrict__ x,
             const float* __restrict__ x2,
             const float* __restrict__ W1,
             const float* __restrict__ b1,
             const float* __restrict__ W2,
             const float* __restrict__ G,
             f32x4* __restrict__ y,
             float* __restrict__ expert_mask,
             float* __restrict__ token_mask,
             float* __restrict__ Pt,      // (B,E) ws
             float4* __restrict__ scal,   // (B) ws
             unsigned* __restrict__ flag) // ws word, memset 0 per call
{
    const int blk = blockIdx.x;
    const int b = blk & (BB - 1);
    const int chunk = blk >> 5;     // 0..255
    const int tid = threadIdx.x;

    __shared__ GateLDS gl;
    __shared__ int rdy;
    __shared__ float4 allscal[BB];

    // pre-issue the 4 streaming loads (overlap HBM ramp with gate/spin)
    const size_t base = (size_t)b * (LL * CC / 4) + ((size_t)chunk << 10) + tid;
    f32x4 v0 = x[base];
    f32x4 v1 = x[base + 256];
    f32x4 v2 = x[base + 512];
    f32x4 v3 = x[base + 768];

    int ready = 1;
    if (chunk == 0) {
        // producer: compute gate for my b and publish
        gate_compute(b, x2, W1, b1, W2, gl);
        if (tid < EE) Pt[b * EE + tid] = gl.pt[tid];
        if (tid == 0)
            scal[b] = make_float4(gl.res[0], gl.res[1], gl.res[2], gl.res[3]);
        __threadfence();
        __syncthreads();
        if (tid == 0)
            __hip_atomic_fetch_add(flag, 1u, __ATOMIC_RELEASE, __HIP_MEMORY_SCOPE_AGENT);
    } else {
        // pin the pre-loads so MachineSink can't move them past the spin
        asm volatile("" : "+v"(v0), "+v"(v1), "+v"(v2), "+v"(v3));
        if (tid == 0) {
            int ok = 0;
            for (int it = 0; it < SPIN_LIMIT; ++it) {
                if (__hip_atomic_load(flag, __ATOMIC_ACQUIRE,
                                      __HIP_MEMORY_SCOPE_AGENT) >= (unsigned)BB) { ok = 1; break; }
                __builtin_amdgcn_s_sleep(8);
            }
            rdy = ok;
        }
        __syncthreads();
        ready = rdy;
        if (ready) {
            if (tid == 0) {
                float4 sc = scal[b];
                gl.res[0] = sc.x; gl.res[1] = sc.y; gl.res[2] = sc.z; gl.res[3] = sc.w;
            }
            __syncthreads();
        } else {
            // pathological dispatch order: compute my own gate (identical bits,
            // no global writes) — guarantees progress without producers.
            gate_compute(b, x2, W1, b1, W2, gl);
        }
    }

    // scale factors for my 4 rows: s = g1*G[b,i1,l] + g2*G[b,i2,l]
    const float g1 = gl.res[0], g2 = gl.res[1];
    const int i1 = __float_as_int(gl.res[2]);
    const int i2 = __float_as_int(gl.res[3]);
    const float* G1 = G + ((size_t)b * EE + i1) * LL;
    const float* G2 = G + ((size_t)b * EE + i2) * LL;
    const int l0 = chunk << 2;
    const float s0 = g1 * G1[l0 + 0] + g2 * G2[l0 + 0];
    const float s1 = g1 * G1[l0 + 1] + g2 * G2[l0 + 1];
    const float s2 = g1 * G1[l0 + 2] + g2 * G2[l0 + 2];
    const float s3 = g1 * G1[l0 + 3] + g2 * G2[l0 + 3];
    v0 *= s0; v1 *= s1; v2 *= s2; v3 *= s3;
    store_stream(v0, &y[base]);
    store_stream(v1, &y[base + 256]);
    store_stream(v2, &y[base + 512]);
    store_stream(v3, &y[base + 768]);

    // --- reduction duties on early blocks ---
    if (chunk == 1 || chunk == 2) {
        // token_mask: 64 blocks x 16 l's. token_mask[l] = sum_b G[b,i1,l]+G[b,i2,l]
        if (ready) {
            if (tid < BB) allscal[tid] = scal[tid];
        } else {
            for (int bb = 0; bb < BB; ++bb) {
                gate_compute(bb, x2, W1, b1, W2, gl);
                if (tid == 0)
                    allscal[bb] = make_float4(gl.res[0], gl.res[1], gl.res[2], gl.res[3]);
            }
        }
        __syncthreads();
        const int slice = ((chunk - 1) << 5) + b;      // 0..63
        const int l = (slice << 4) + (tid >> 4);
        const int part = tid & 15;
        float acc = 0.f;
#pragma unroll
        for (int q = 0; q < 2; ++q) {
            const int bb = part * 2 + q;
            const int j1 = __float_as_int(allscal[bb].z);
            const int j2 = __float_as_int(allscal[bb].w);
            acc += G[((size_t)bb * EE + j1) * LL + l];
            acc += G[((size_t)bb * EE + j2) * LL + l];
        }
#pragma unroll
        for (int off = 8; off; off >>= 1) acc += __shfl_xor(acc, off);
        if (part == 0) token_mask[l] = acc;
    } else if (chunk == 3 && b == 0) {
        // expert_mask[e] = sum_b Pt[b,e]
        if (ready) {
            if (tid < EE) {
                float acc = 0.f;
#pragma unroll 8
                for (int bb = 0; bb < BB; ++bb) acc += Pt[bb * EE + tid];
                expert_mask[tid] = acc;
            }
        } else {
            float acc = 0.f;
            for (int bb = 0; bb < BB; ++bb) {
                gate_compute(bb, x2, W1, b1, W2, gl);
                if (tid < EE) acc += gl.pt[tid];
            }
            if (tid < EE) expert_mask[tid] = acc;
        }
    }
}

extern "C" void kernel_launch(void* const* d_in, const int* in_sizes, int n_in,
                              void* d_out, int out_size, void* d_ws, size_t ws_size,
                              hipStream_t stream) {
    const float* x  = (const float*)d_in[0];  // (32,1024,1024)
    const float* x2 = (const float*)d_in[1];  // (32,8)
    const float* G  = (const float*)d_in[2];  // (32,64,1024)
    const float* W1 = (const float*)d_in[3];  // (8,1024)
    const float* b1 = (const float*)d_in[4];  // (1024)
    const float* W2 = (const float*)d_in[5];  // (1024,128)
    // d_in[6] = k (==2, hardcoded)

    float* y           = (float*)d_out;                  // (32,1024,1024)
    float* expert_mask = y + (size_t)BB * LL * CC;       // (1,64)
    float* token_mask  = expert_mask + EE;               // (1,1024)

    unsigned* flag = (unsigned*)d_ws;                    // 1 word
    float4*   scal = (float4*)((char*)d_ws + 256);       // 32 x float4
    float*    Pt   = (float*)((char*)d_ws + 768);        // 32 x 64 floats

    hipMemsetAsync(d_ws, 0, 4, stream);   // reset flag (graph-capture legal)

    fused_kernel<<<NBLK, 256, 0, stream>>>(
        (const f32x4*)x, x2, W1, b1, W2, G, (f32x4*)y,
        expert_mask, token_mask, Pt, scal, flag);
}

// Round 10
// 50.295 us; speedup vs baseline: 7.7202x; 7.7202x over previous
//
#include <hip/hip_runtime.h>
#include <math.h>

#define BB 32
#define LL 1024
#define CC 1024
#define EE 64
#define TASKS 8

typedef float f32x4 __attribute__((ext_vector_type(4)));

__device__ __forceinline__ float gelu_exact(float x) {
    // gelu(x) = 0.5*x*(1+erf(x/sqrt(2))), approximate=False
    return 0.5f * x * (1.0f + erff(x * 0.7071067811865476f));
}

// Streaming store: sc0 sc1 nt — measured -3us vs __builtin_nontemporal_store
// (does NOT reduce LLC allocation / FETCH, but avoids L2 write-allocate cost).
__device__ __forceinline__ void store_stream(f32x4 v, f32x4* p) {
    asm volatile("global_store_dwordx4 %0, %1, off sc0 sc1 nt"
                 :: "v"(p), "v"(v) : "memory");
}

// One block (1024 threads) per batch row:
// hgate -> logits (coalesced, wave-parallel) -> softmax -> top-2 -> P_t
// -> fused s/tm row computation.
__global__ void __launch_bounds__(1024)
gate_kernel(const float* __restrict__ x2,   // (B,8)
            const float* __restrict__ W1,   // (8,1024)
            const float* __restrict__ b1,   // (1024)
            const float* __restrict__ W2,   // (1024,128)
            const float* __restrict__ G,    // (B,E,L)
            float* __restrict__ Pt,         // (B,E) ws
            float* __restrict__ s,          // (B,L) ws
            float* __restrict__ tm)         // (B,L) ws
{
    const int b = blockIdx.x;
    const int tid = threadIdx.x;
    __shared__ float hg[CC];
    __shared__ float part[16][EE];
    __shared__ float sg[2];
    __shared__ int   si[2];

    // hgate = gelu(x2 @ W1 + b1): one c per thread
    {
        const int c = tid;
        float acc = b1[c];
#pragma unroll
        for (int t = 0; t < TASKS; ++t) acc += x2[b * TASKS + t] * W1[t * CC + c];
        hg[c] = gelu_exact(acc);
    }
    __syncthreads();

    // logits[e] = sum_c hg[c] * W2[c,e]
    // wave w handles c = w, w+16, ..., lane = e -> coalesced 256B wave loads
    const int wave = tid >> 6;
    const int lane = tid & 63;
    {
        float acc = 0.f;
#pragma unroll
        for (int i = 0; i < 64; ++i) {
            const int c = wave + (i << 4);
            acc += hg[c] * W2[c * 128 + lane];
        }
        part[wave][lane] = acc;
    }
    __syncthreads();

    // wave 0 (64 lanes == 64 experts): cross-wave reduce, softmax, top-2
    if (tid < EE) {
        float v = 0.f;
#pragma unroll
        for (int w = 0; w < 16; ++w) v += part[w][tid];

        float m = v;
#pragma unroll
        for (int off = 32; off; off >>= 1) m = fmaxf(m, __shfl_xor(m, off));
        float ex = expf(v - m);
        float sum = ex;
#pragma unroll
        for (int off = 32; off; off >>= 1) sum += __shfl_xor(sum, off);
        float p = ex / sum + 1e-4f;

        // argmax #1 (ties -> lowest index, matching lax.top_k)
        float bv = p; int bi = tid;
#pragma unroll
        for (int off = 32; off; off >>= 1) {
            float ov = __shfl_xor(bv, off);
            int   oi = __shfl_xor(bi, off);
            if (ov > bv || (ov == bv && oi < bi)) { bv = ov; bi = oi; }
        }
        // argmax #2 (exclude winner lane; p > 0 so -1 acts as -inf)
        float p2 = (tid == bi) ? -1.f : p;
        float bv2 = p2; int bi2 = tid;
#pragma unroll
        for (int off = 32; off; off >>= 1) {
            float ov = __shfl_xor(bv2, off);
            int   oi = __shfl_xor(bi2, off);
            if (ov > bv2 || (ov == bv2 && oi < bi2)) { bv2 = ov; bi2 = oi; }
        }
        Pt[b * EE + tid] = (p >= bv2) ? p : 0.f;
        if (tid == 0) {
            sg[0] = bv;  sg[1] = bv2;
            si[0] = bi;  si[1] = bi2;
        }
    }
    __syncthreads();

    // fused s/tm rows: s[b,l] = g1*G[b,i1,l] + g2*G[b,i2,l]; tm = G1+G2
    {
        const float g1 = sg[0], g2 = sg[1];
        const int i1 = si[0], i2 = si[1];
        const float* G1 = G + ((size_t)b * EE + i1) * LL;
        const float* G2 = G + ((size_t)b * EE + i2) * LL;
        const int l = tid;
        const float a = G1[l];
        const float c = G2[l];
        s[b * LL + l]  = g1 * a + g2 * c;
        tm[b * LL + l] = a + c;
    }
}

// y[b,l,c] = x[b,l,c] * s[b,l] — the 256 MB streaming kernel.
// 8192 blocks (4 scheduling rounds per CU slot) smooth the completion tail;
// unroll-2 pairs keep 2 independent load/store chains in flight without a
// vmcnt burst wall. Blocks 0..15 each reduce a 64-entry slice of token_mask,
// block 16 reduces expert_mask (first-dispatched blocks absorb the extra work).
__global__ void __launch_bounds__(256)
scale_kernel(const f32x4* __restrict__ x,
             const float* __restrict__ s,
             f32x4* __restrict__ y, int n4,
             const float* __restrict__ Pt,   // (B,E)
             const float* __restrict__ tm,   // (B,L)
             float* __restrict__ expert_mask,
             float* __restrict__ token_mask)
{
    if (blockIdx.x < 16) {
        const int t = threadIdx.x;
        if (t < 64) {
            const int l = (blockIdx.x << 6) + t;
            float acc = 0.f;
#pragma unroll 8
            for (int b = 0; b < BB; ++b) acc += tm[b * LL + l];
            token_mask[l] = acc;
        }
    } else if (blockIdx.x == 16) {
        const int t = threadIdx.x;
        if (t < EE) {
            float acc = 0.f;
#pragma unroll 8
            for (int b = 0; b < BB; ++b) acc += Pt[b * EE + t];
            expert_mask[t] = acc;
        }
    }

    const int T = gridDim.x * blockDim.x;      // 8192*256 = 2,097,152
    int i = blockIdx.x * blockDim.x + threadIdx.x;
    // n4 / T == 4 for this shape -> exactly 2 unroll-2 iterations, no tail.
    for (; i + T < n4; i += 2 * T) {
        const int i0 = i, i1 = i + T;
        const float s0 = s[i0 >> 8];
        const float s1 = s[i1 >> 8];
        f32x4 v0 = x[i0];
        f32x4 v1 = x[i1];
        v0 *= s0;
        v1 *= s1;
        store_stream(v0, &y[i0]);
        store_stream(v1, &y[i1]);
    }
    for (; i < n4; i += T) {   // tail (unused for this shape)
        f32x4 v = x[i];
        v *= s[i >> 8];
        store_stream(v, &y[i]);
    }
}

extern "C" void kernel_launch(void* const* d_in, const int* in_sizes, int n_in,
                              void* d_out, int out_size, void* d_ws, size_t ws_size,
                              hipStream_t stream) {
    const float* x  = (const float*)d_in[0];  // (32,1024,1024)
    const float* x2 = (const float*)d_in[1];  // (32,8)
    const float* G  = (const float*)d_in[2];  // (32,64,1024)
    const float* W1 = (const float*)d_in[3];  // (8,1024)
    const float* b1 = (const float*)d_in[4];  // (1024)
    const float* W2 = (const float*)d_in[5];  // (1024,128)
    // d_in[6] = k (==2, hardcoded)

    float* y           = (float*)d_out;                  // (32,1024,1024)
    float* expert_mask = y + (size_t)BB * LL * CC;       // (1,64)
    float* token_mask  = expert_mask + EE;               // (1,1024)

    float* s  = (float*)d_ws;        // B*L
    float* tm = s + BB * LL;         // B*L
    float* Pt = tm + BB * LL;        // B*E

    gate_kernel<<<BB, 1024, 0, stream>>>(x2, W1, b1, W2, G, Pt, s, tm);

    const int n4 = BB * LL * CC / 4;
    scale_kernel<<<8192, 256, 0, stream>>>((const f32x4*)x, s, (f32x4*)y, n4,
                                           Pt, tm, expert_mask, token_mask);
}